// Round 10
// baseline (115.720 us; speedup 1.0000x reference)
//
#include <hip/hip_runtime.h>
#include <math.h>

#define B 64
#define T 4096
#define D 512
#define NCH 32            // 128-row chunks per batch row
#define CHT (T / NCH)     // 128 t per chunk
#define WSTRIP 32         // t-rows per wave
#define KBATCH 2          // K rows per pipeline batch per wave (K1)
#define VB 2              // V rows per pipeline batch per wave (K3)

typedef __attribute__((address_space(1))) const void global_cv;
typedef __attribute__((address_space(3))) void lds_v;

__device__ __forceinline__ float wave_sum64(float v) {
#pragma unroll
    for (int off = 32; off; off >>= 1)
        v += __shfl_xor(v, off, 64);
    return v;
}

// Async-stage one 2KB row into LDS: 2 x (64 lanes x 16B) global_load_lds.
// LDS dest is wave-uniform base (HW adds lane*16); global src is per-lane.
// +2 vmcnt per call per wave.
__device__ __forceinline__ void stage_row(const float* __restrict__ gsrc_row,
                                          float* lds_row, int lane) {
    __builtin_amdgcn_global_load_lds((global_cv*)(gsrc_row + lane * 4),
                                     (lds_v*)(lds_row), 16, 0, 0);
    __builtin_amdgcn_global_load_lds((global_cv*)(gsrc_row + 256 + lane * 4),
                                     (lds_v*)(lds_row + 256), 16, 0, 0);
}

// K1: DMA-pipelined energy+exp. grid = B*32, block = 256 (4 waves x 32-row
// strip). Live rows compacted per wave; K rows stream through a per-wave
// 2x2-row LDS double buffer (counted vmcnt(4), no in-loop barriers).
// g staged in LDS; attn written as ONE coalesced 128B store per wave
// (zeros included). 32KB LDS -> 4 blocks/CU.
__global__ __launch_bounds__(256) void energy_exp_kernel(const float* __restrict__ q,
                                                         const float* __restrict__ k,
                                                         const int* __restrict__ mask,
                                                         float* __restrict__ attn,
                                                         float* __restrict__ chunk_sums) {
    const float INV_SCALE = 0.04419417382415922f;  // 1/sqrt(512)

    __shared__ __align__(16) float kbuf[2][4][KBATCH][D];   // 32 KB
    __shared__ int sm_list[4][WSTRIP + KBATCH];
    __shared__ float sm_g[4][WSTRIP];
    __shared__ float sred[4];

    int blk = blockIdx.x;
    int b = blk >> 5;
    int ch = blk & 31;
    int wave = threadIdx.x >> 6;
    int lane = threadIdx.x & 63;

    const float* qb = q + b * D;
    float4 qa = *(const float4*)(qb + lane * 4);
    float4 qc = *(const float4*)(qb + 256 + lane * 4);

    int t0 = ch * CHT + wave * WSTRIP;
    const float* kbase = k + ((size_t)b * T + t0) * D;

    // 32-row mask bitmap + order-stable compaction (wave-local LDS list)
    int mv = (lane < WSTRIP) ? mask[b * T + t0 + lane] : 0;
    unsigned int mbits = (unsigned int)__ballot(mv != 0);
    int cnt = __popc(mbits);
    int row0 = (cnt > 0) ? (__ffs(mbits) - 1) : 0;
    if (lane < WSTRIP) {
        sm_g[wave][lane] = 0.0f;           // masked rows stay exactly 0
        if (mv != 0) {
            int pre = __popc(mbits & ((1u << lane) - 1u));
            sm_list[wave][pre] = lane;
        }
    }
    if (lane < KBATCH) sm_list[wave][cnt + lane] = row0;  // pad slots (L2 hit)

    int ngrp = (cnt + KBATCH - 1) >> 1;

    // prologue: stage batches 0 and 1 (2 rows = 4 vmcnt each, per wave)
    if (ngrp > 0) {
#pragma unroll
        for (int r = 0; r < KBATCH; ++r)
            stage_row(kbase + (size_t)sm_list[wave][r] * D, &kbuf[0][wave][r][0], lane);
    }
    if (ngrp > 1) {
#pragma unroll
        for (int r = 0; r < KBATCH; ++r)
            stage_row(kbase + (size_t)sm_list[wave][KBATCH + r] * D, &kbuf[1][wave][r][0], lane);
    }

    int rown = lane >> 5;   // which of the 2 rows this lane owns post-butterfly
    float gsum = 0.f;

#pragma unroll 1
    for (int i = 0; i < ngrp; ++i) {
        if (i + 1 < ngrp) asm volatile("s_waitcnt vmcnt(4)" ::: "memory");
        else              asm volatile("s_waitcnt vmcnt(0)" ::: "memory");

        float d2[KBATCH];
#pragma unroll
        for (int rr = 0; rr < KBATCH; ++rr) {
            const float* buf = &kbuf[i & 1][wave][rr][0];
            float4 ka = *(const float4*)&buf[lane * 4];
            float4 kc = *(const float4*)&buf[256 + lane * 4];
            d2[rr] = ka.x * qa.x + ka.y * qa.y + ka.z * qa.z + ka.w * qa.w
                   + kc.x * qc.x + kc.y * qc.y + kc.z * qc.z + kc.w * qc.w;
        }
        // ds_reads of this buffer complete before re-staging over it
        asm volatile("s_waitcnt lgkmcnt(0)" ::: "memory");
        if (i + 2 < ngrp) {
            int s0 = (i + 2) * KBATCH;
#pragma unroll
            for (int r = 0; r < KBATCH; ++r)
                stage_row(kbase + (size_t)sm_list[wave][s0 + r] * D,
                          &kbuf[i & 1][wave][r][0], lane);
        }

        // 2-row multiplexed butterfly: full dots in 6 shuffles
        bool b5 = (lane & 32) != 0;
        float u = b5 ? d2[1] : d2[0];
        float s = b5 ? d2[0] : d2[1];
        float h = u + __shfl_xor(s, 32, 64);
        h += __shfl_xor(h, 16, 64);
        h += __shfl_xor(h, 8, 64);
        h += __shfl_xor(h, 4, 64);
        h += __shfl_xor(h, 2, 64);
        h += __shfl_xor(h, 1, 64);
        // h = dot for slot (i*2 + rown), replicated on 32 lanes

        int slot = i * KBATCH + rown;
        float gval = 0.f;
        if (slot < cnt) {
            gval = __expf(h * INV_SCALE);
            if ((lane & 31) == 0)
                sm_g[wave][sm_list[wave][slot]] = gval;
        }
        gsum += gval;
    }

    // ONE coalesced 128B attn store per wave (unnormalized; K3 rescales)
    if (lane < WSTRIP)
        attn[(size_t)b * T + t0 + lane] = sm_g[wave][lane];

    // wave chunk-sum (each live row's g replicated on 32 lanes -> /32)
    float ws = wave_sum64(gsum) * 0.03125f;
    if (lane == 0) sred[wave] = ws;
    __syncthreads();
    if (threadIdx.x == 0)
        chunk_sums[blk] = (sred[0] + sred[1]) + (sred[2] + sred[3]);
}

// K3: per-wave DMA-pipelined V accumulation. grid = B*NCH, block = 256.
// Each wave owns a 32-row strip: compact its live rows, stream V rows
// through a per-wave 2x2-row LDS double buffer (counted vmcnt(4), ZERO
// in-loop barriers). Wave partials combined once via LDS at the end.
// Denominator rebuilt per wave via identical fixed-order butterfly.
__global__ __launch_bounds__(256) void context_partial_kernel(float* __restrict__ attn,
                                                              const float* __restrict__ v,
                                                              const float* __restrict__ chunk_sums,
                                                              float* __restrict__ partial) {
    __shared__ __align__(16) float vbuf[2][4][VB][D];   // 32 KB
    __shared__ int   rows[4][WSTRIP + VB];
    __shared__ float av[4][WSTRIP + VB];
    __shared__ float sacc[4][D];                        // 8 KB

    int blk = blockIdx.x;
    int b = blk >> 5;
    int ch = blk & 31;
    int tid = threadIdx.x;
    int wave = tid >> 6;
    int lane = tid & 63;

    float cs = (lane < NCH) ? chunk_sums[b * NCH + lane] : 0.f;
    float denom = wave_sum64(cs);
    float inv = 1.0f / denom;

    int t0 = ch * CHT + wave * WSTRIP;

    // read this wave's strip of unnormalized attn; compact non-zero rows
    float a = (lane < WSTRIP) ? attn[(size_t)b * T + t0 + lane] : 0.f;
    unsigned long long bl = __ballot(a != 0.0f);
    int cnt = __popcll(bl);
    int row0 = (cnt > 0) ? (int)(__ffsll((unsigned long long)bl) - 1) : 0;
    if (a != 0.0f) {
        int pre = __popcll(bl & ((1ull << lane) - 1ull));
        rows[wave][pre] = lane;
        av[wave][pre] = a;
    }
    if (lane < VB) {                  // pad slots: first live row (L2 hit), a=0
        rows[wave][cnt + lane] = row0;
        av[wave][cnt + lane] = 0.0f;
    }

    int nb = (cnt + VB - 1) >> 1;
    const float* vw = v + ((size_t)b * T + t0) * D;

    // prologue: stage batches 0 and 1
    if (nb > 0) {
#pragma unroll
        for (int r = 0; r < VB; ++r)
            stage_row(vw + (size_t)rows[wave][r] * D, &vbuf[0][wave][r][0], lane);
    }
    if (nb > 1) {
#pragma unroll
        for (int r = 0; r < VB; ++r)
            stage_row(vw + (size_t)rows[wave][VB + r] * D, &vbuf[1][wave][r][0], lane);
    }

    float4 accA = {0.f, 0.f, 0.f, 0.f}, accC = {0.f, 0.f, 0.f, 0.f};
#pragma unroll 1
    for (int i = 0; i < nb; ++i) {
        if (i + 1 < nb) asm volatile("s_waitcnt vmcnt(4)" ::: "memory");
        else            asm volatile("s_waitcnt vmcnt(0)" ::: "memory");

        float a0 = av[wave][i * 2];
        float a1 = av[wave][i * 2 + 1];
        const float* b0 = &vbuf[i & 1][wave][0][0];
        const float* b1 = &vbuf[i & 1][wave][1][0];
        float4 v0a = *(const float4*)&b0[lane * 4];
        float4 v0c = *(const float4*)&b0[256 + lane * 4];
        float4 v1a = *(const float4*)&b1[lane * 4];
        float4 v1c = *(const float4*)&b1[256 + lane * 4];
        accA.x += a0 * v0a.x + a1 * v1a.x;
        accA.y += a0 * v0a.y + a1 * v1a.y;
        accA.z += a0 * v0a.z + a1 * v1a.z;
        accA.w += a0 * v0a.w + a1 * v1a.w;
        accC.x += a0 * v0c.x + a1 * v1c.x;
        accC.y += a0 * v0c.y + a1 * v1c.y;
        accC.z += a0 * v0c.z + a1 * v1c.z;
        accC.w += a0 * v0c.w + a1 * v1c.w;

        // ds_reads of this buffer complete before re-staging over it
        asm volatile("s_waitcnt lgkmcnt(0)" ::: "memory");
        if (i + 2 < nb) {
            int s0 = (i + 2) * VB;
#pragma unroll
            for (int r = 0; r < VB; ++r)
                stage_row(vw + (size_t)rows[wave][s0 + r] * D,
                          &vbuf[i & 1][wave][r][0], lane);
        }
    }

    // normalized attn write-back (coalesced 128B per wave)
    if (lane < WSTRIP)
        attn[(size_t)b * T + t0 + lane] = a * inv;

    // combine 4 wave partials -> one partial row per block (inv applied)
    *(float4*)(&sacc[wave][lane * 4]) = accA;
    *(float4*)(&sacc[wave][256 + lane * 4]) = accC;
    __syncthreads();

    int c0 = tid * 2;
    float2 p;
    p.x = ((sacc[0][c0]     + sacc[1][c0])     + (sacc[2][c0]     + sacc[3][c0])) * inv;
    p.y = ((sacc[0][c0 + 1] + sacc[1][c0 + 1]) + (sacc[2][c0 + 1] + sacc[3][c0 + 1])) * inv;
    *(float2*)(partial + (size_t)(b * NCH + ch) * D + c0) = p;
}

// K4: reduce 32 partial rows -> context. grid = B, block = 256.
__global__ __launch_bounds__(256) void context_reduce_kernel(const float* __restrict__ partial,
                                                             float* __restrict__ ctx) {
    int b = blockIdx.x;
    int tid = threadIdx.x;
    int d0 = tid * 2;
    float2 acc = {0.f, 0.f};
#pragma unroll 8
    for (int j = 0; j < NCH; ++j) {
        float2 p = *(const float2*)(partial + (size_t)(b * NCH + j) * D + d0);
        acc.x += p.x;
        acc.y += p.y;
    }
    *(float2*)(ctx + (size_t)b * D + d0) = acc;
}

extern "C" void kernel_launch(void* const* d_in, const int* in_sizes, int n_in,
                              void* d_out, int out_size, void* d_ws, size_t ws_size,
                              hipStream_t stream) {
    const float* q    = (const float*)d_in[0];
    const float* k    = (const float*)d_in[1];
    const float* v    = (const float*)d_in[2];
    const int*   mask = (const int*)d_in[3];

    float* ctx  = (float*)d_out;            // [B, D]
    float* attn = (float*)d_out + B * D;    // [B, T]

    float* chunk_sums = (float*)d_ws;            // B*NCH floats = 8 KB
    float* partial    = (float*)d_ws + 8192;     // [B*NCH, D] = 4.2 MB

    energy_exp_kernel<<<B * NCH, 256, 0, stream>>>(q, k, mask, attn, chunk_sums);
    context_partial_kernel<<<B * NCH, 256, 0, stream>>>(attn, v, chunk_sums, partial);
    context_reduce_kernel<<<B, 256, 0, stream>>>(partial, ctx);
}

// Round 11
// 113.853 us; speedup vs baseline: 1.0164x; 1.0164x over previous
//
#include <hip/hip_runtime.h>
#include <math.h>

#define B 64
#define T 4096
#define D 512
#define NCH 32            // 128-row chunks per batch row
#define CHT (T / NCH)     // 128 t per chunk
#define WSTRIP 32         // t-rows per wave
#define KBATCH 4          // K rows per pipeline batch per wave (K1)
#define VBATCH 8          // V rows per pipeline batch per block (K3)
#define K1_CPB 4          // chunks per block, K1 (512 blocks = 2/CU resident)
#define K3_CPB 2          // chunks per block, K3 (1024 blocks = 4/CU resident)

typedef __attribute__((address_space(1))) const void global_cv;
typedef __attribute__((address_space(3))) void lds_v;

__device__ __forceinline__ float wave_sum64(float v) {
#pragma unroll
    for (int off = 32; off; off >>= 1)
        v += __shfl_xor(v, off, 64);
    return v;
}

// Async-stage one 2KB row into LDS: 2 x (64 lanes x 16B) global_load_lds.
// LDS dest is wave-uniform base (HW adds lane*16); global src is per-lane.
// +2 vmcnt per call per wave.
__device__ __forceinline__ void stage_row(const float* __restrict__ gsrc_row,
                                          float* lds_row, int lane) {
    __builtin_amdgcn_global_load_lds((global_cv*)(gsrc_row + lane * 4),
                                     (lds_v*)(lds_row), 16, 0, 0);
    __builtin_amdgcn_global_load_lds((global_cv*)(gsrc_row + 256 + lane * 4),
                                     (lds_v*)(lds_row + 256), 16, 0, 0);
}

// K1 (R8 body, persistent blocks): DMA-pipelined energy+exp. grid = 512,
// block = 256. Each block owns 4 consecutive chunks of one b (Q loaded once).
// Per chunk: 4 waves x 32-row strip; live rows compacted per wave; K rows
// stream through a per-wave 2x4-row LDS double buffer (counted vmcnt(8),
// no in-loop barriers). Masked rows never read.
__global__ __launch_bounds__(256) void energy_exp_kernel(const float* __restrict__ q,
                                                         const float* __restrict__ k,
                                                         const int* __restrict__ mask,
                                                         float* __restrict__ attn,
                                                         float* __restrict__ chunk_sums) {
    const float INV_SCALE = 0.04419417382415922f;  // 1/sqrt(512)

    __shared__ __align__(16) float kbuf[2][4][KBATCH][D];   // 64 KB
    __shared__ int sm_list[4][WSTRIP + KBATCH];
    __shared__ float sred[4];

    int j = blockIdx.x;            // 0..511
    int b = j >> 3;
    int ch0 = (j & 7) * K1_CPB;
    int wave = threadIdx.x >> 6;
    int lane = threadIdx.x & 63;

    const float* qb = q + b * D;
    float4 qa = *(const float4*)(qb + lane * 4);
    float4 qc = *(const float4*)(qb + 256 + lane * 4);

    // slot owned by this lane after the 4-row butterfly: bits {5,4} -> {0,1,2,3}
    int r2 = ((lane >> 5) & 1) | (((lane >> 4) & 1) << 1);

#pragma unroll 1
    for (int c4 = 0; c4 < K1_CPB; ++c4) {
        int ch = ch0 + c4;
        int t0 = ch * CHT + wave * WSTRIP;
        const float* kbase = k + ((size_t)b * T + t0) * D;

        __syncthreads();   // protect sred across chunk iterations

        // 32-row mask bitmap + order-stable compaction (wave-local LDS list)
        int mv = (lane < WSTRIP) ? mask[b * T + t0 + lane] : 0;
        unsigned int mbits = (unsigned int)__ballot(mv != 0);
        int cnt = __popc(mbits);
        int row0 = (cnt > 0) ? (__ffs(mbits) - 1) : 0;
        if (lane < WSTRIP) {
            if (mv != 0) {
                int pre = __popc(mbits & ((1u << lane) - 1u));
                sm_list[wave][pre] = lane;
            } else {
                attn[(size_t)b * T + t0 + lane] = 0.0f;  // exact 0 for masked rows
            }
        }
        if (lane < KBATCH) sm_list[wave][cnt + lane] = row0;  // pad slots

        int ngrp = (cnt + KBATCH - 1) >> 2;

        // prologue: stage batches 0 and 1 (4 rows = 8 vmcnt each, per wave)
        if (ngrp > 0) {
#pragma unroll
            for (int r = 0; r < KBATCH; ++r)
                stage_row(kbase + (size_t)sm_list[wave][r] * D, &kbuf[0][wave][r][0], lane);
        }
        if (ngrp > 1) {
#pragma unroll
            for (int r = 0; r < KBATCH; ++r)
                stage_row(kbase + (size_t)sm_list[wave][KBATCH + r] * D, &kbuf[1][wave][r][0], lane);
        }

        float gsum = 0.f;

#pragma unroll 1
        for (int i = 0; i < ngrp; ++i) {
            if (i + 1 < ngrp) asm volatile("s_waitcnt vmcnt(8)" ::: "memory");
            else              asm volatile("s_waitcnt vmcnt(0)" ::: "memory");

            const float (*buf)[D] = kbuf[i & 1][wave];
            float d4[KBATCH];
#pragma unroll
            for (int rr = 0; rr < KBATCH; ++rr) {
                float4 ka = *(const float4*)&buf[rr][lane * 4];
                float4 kc = *(const float4*)&buf[rr][256 + lane * 4];
                d4[rr] = ka.x * qa.x + ka.y * qa.y + ka.z * qa.z + ka.w * qa.w
                       + kc.x * qc.x + kc.y * qc.y + kc.z * qc.z + kc.w * qc.w;
            }
            // ds_reads of this buffer complete before re-staging over it
            asm volatile("s_waitcnt lgkmcnt(0)" ::: "memory");
            if (i + 2 < ngrp) {
                int s0 = (i + 2) * KBATCH;
#pragma unroll
                for (int r = 0; r < KBATCH; ++r)
                    stage_row(kbase + (size_t)sm_list[wave][s0 + r] * D,
                              &kbuf[i & 1][wave][r][0], lane);
            }

            // multiplexed butterfly: 4 slots x 64 lanes -> full dots in 7 shuffles
            bool b5 = (lane & 32) != 0;
            float e[2];
#pragma unroll
            for (int jj = 0; jj < 2; ++jj) {
                float u = b5 ? d4[2*jj+1] : d4[2*jj];
                float s = b5 ? d4[2*jj]   : d4[2*jj+1];
                e[jj] = u + __shfl_xor(s, 32, 64);
            }
            bool b4 = (lane & 16) != 0;
            float u = b4 ? e[1] : e[0];
            float s = b4 ? e[0] : e[1];
            float h = u + __shfl_xor(s, 16, 64);
            h += __shfl_xor(h, 8, 64);
            h += __shfl_xor(h, 4, 64);
            h += __shfl_xor(h, 2, 64);
            h += __shfl_xor(h, 1, 64);
            // h = dot for slot (i*4 + r2), replicated on 16 lanes

            int slot = i * KBATCH + r2;
            float gval = 0.f;
            if (slot < cnt) {
                gval = __expf(h * INV_SCALE);
                if ((lane & 15) == 0) {
                    int row = sm_list[wave][slot];
                    attn[(size_t)b * T + t0 + row] = gval;  // unnormalized
                }
            }
            gsum += gval;
        }

        // wave chunk-sum (each live row's g replicated on 16 lanes -> /16)
        float ws = wave_sum64(gsum) * 0.0625f;
        if (lane == 0) sred[wave] = ws;
        __syncthreads();
        if (threadIdx.x == 0)
            chunk_sums[b * NCH + ch] = (sred[0] + sred[1]) + (sred[2] + sred[3]);
    }
}

// K3 (R8 body, persistent blocks): DMA-pipelined V accumulation. grid = 1024,
// block = 256. Each block owns 2 consecutive chunks of one b (denominator
// butterfly hoisted). Per chunk: live rows compacted (order-stable); V rows
// streamed through a 2x8-row block-wide LDS double buffer (global_load_lds,
// counted vmcnt(4) + raw s_barrier). Accumulation in list (=t) order.
__global__ __launch_bounds__(256) void context_partial_kernel(float* __restrict__ attn,
                                                              const float* __restrict__ v,
                                                              const float* __restrict__ chunk_sums,
                                                              float* __restrict__ partial) {
    __shared__ __align__(16) float vbuf[2][VBATCH][D];   // 32 KB
    __shared__ float sa_raw[CHT];
    __shared__ int   rows[CHT + VBATCH];
    __shared__ float avals[CHT + VBATCH];
    __shared__ int   scnt;

    int j = blockIdx.x;            // 0..1023
    int b = j >> 4;
    int ch0 = (j & 15) * K3_CPB;
    int tid = threadIdx.x;
    int wave = tid >> 6;
    int lane = tid & 63;

    // denominator: fixed-order butterfly, identical in every block of this b
    float cs = (lane < NCH) ? chunk_sums[b * NCH + lane] : 0.f;
    float denom = wave_sum64(cs);
    float inv = 1.0f / denom;

#pragma unroll 1
    for (int c2 = 0; c2 < K3_CPB; ++c2) {
        int ch = ch0 + c2;

        __syncthreads();   // prev iteration's readers of sa_raw/rows/avals done

        if (tid < CHT) sa_raw[tid] = attn[(size_t)b * T + ch * CHT + tid];
        __syncthreads();

        if (wave == 0) {
            // order-stable compaction of 128 rows (two 64-row passes, wave 0)
            float a0 = sa_raw[lane];
            unsigned long long bl0 = __ballot(a0 != 0.0f);
            int c0n = __popcll(bl0);
            if (a0 != 0.0f) {
                int p = __popcll(bl0 & ((1ull << lane) - 1ull));
                rows[p] = lane; avals[p] = a0;
            }
            float a1 = sa_raw[64 + lane];
            unsigned long long bl1 = __ballot(a1 != 0.0f);
            int c1n = __popcll(bl1);
            if (a1 != 0.0f) {
                int p = c0n + __popcll(bl1 & ((1ull << lane) - 1ull));
                rows[p] = 64 + lane; avals[p] = a1;
            }
            int cnt = c0n + c1n;
            if (lane < VBATCH) {       // pad slots: re-stage row[0] (L2 hit), a=0
                int safe0 = (cnt > 0) ? rows[0] : 0;
                rows[cnt + lane] = safe0;
                avals[cnt + lane] = 0.0f;
            }
            if (lane == 0) scnt = cnt;
        }
        __syncthreads();

        int cnt = scnt;
        int nb = (cnt + VBATCH - 1) / VBATCH;
        const float* vchunk = v + ((size_t)b * T + ch * CHT) * D;

        // prologue: stage batches 0 and 1 (each wave stages its 2 rows = 4 vmcnt)
        if (nb > 0) {
            int s0 = wave * 2;
            stage_row(vchunk + (size_t)rows[s0] * D,     &vbuf[0][wave * 2][0],     lane);
            stage_row(vchunk + (size_t)rows[s0 + 1] * D, &vbuf[0][wave * 2 + 1][0], lane);
        }
        if (nb > 1) {
            int s0 = VBATCH + wave * 2;
            stage_row(vchunk + (size_t)rows[s0] * D,     &vbuf[1][wave * 2][0],     lane);
            stage_row(vchunk + (size_t)rows[s0 + 1] * D, &vbuf[1][wave * 2 + 1][0], lane);
        }

        float2 acc = {0.f, 0.f};
        int c0 = tid * 2;
#pragma unroll 1
        for (int i = 0; i < nb; ++i) {
            if (i + 1 < nb) asm volatile("s_waitcnt vmcnt(4)" ::: "memory");
            else            asm volatile("s_waitcnt vmcnt(0)" ::: "memory");
            __builtin_amdgcn_s_barrier();   // all waves' batch-i stages landed

            const float (*buf)[D] = vbuf[i & 1];
            int base = i * VBATCH;
#pragma unroll
            for (int r = 0; r < VBATCH; ++r) {
                float a = avals[base + r];                    // LDS broadcast
                float2 vv = *(const float2*)&buf[r][c0];      // ds_read_b64
                acc.x += a * vv.x;
                acc.y += a * vv.y;
            }
            __builtin_amdgcn_s_barrier();   // all reads of buf done before overwrite

            if (i + 2 < nb) {
                int s0 = (i + 2) * VBATCH + wave * 2;
                stage_row(vchunk + (size_t)rows[s0] * D,     &vbuf[i & 1][wave * 2][0],     lane);
                stage_row(vchunk + (size_t)rows[s0 + 1] * D, &vbuf[i & 1][wave * 2 + 1][0], lane);
            }
        }

        acc.x *= inv; acc.y *= inv;
        *(float2*)(partial + (size_t)(b * NCH + ch) * D + c0) = acc;

        if (tid < CHT)
            attn[(size_t)b * T + ch * CHT + tid] = sa_raw[tid] * inv;
    }
}

// K4: reduce 32 partial rows -> context. grid = B, block = 256.
__global__ __launch_bounds__(256) void context_reduce_kernel(const float* __restrict__ partial,
                                                             float* __restrict__ ctx) {
    int b = blockIdx.x;
    int tid = threadIdx.x;
    int d0 = tid * 2;
    float2 acc = {0.f, 0.f};
#pragma unroll 8
    for (int j = 0; j < NCH; ++j) {
        float2 p = *(const float2*)(partial + (size_t)(b * NCH + j) * D + d0);
        acc.x += p.x;
        acc.y += p.y;
    }
    *(float2*)(ctx + (size_t)b * D + d0) = acc;
}

extern "C" void kernel_launch(void* const* d_in, const int* in_sizes, int n_in,
                              void* d_out, int out_size, void* d_ws, size_t ws_size,
                              hipStream_t stream) {
    const float* q    = (const float*)d_in[0];
    const float* k    = (const float*)d_in[1];
    const float* v    = (const float*)d_in[2];
    const int*   mask = (const int*)d_in[3];

    float* ctx  = (float*)d_out;            // [B, D]
    float* attn = (float*)d_out + B * D;    // [B, T]

    float* chunk_sums = (float*)d_ws;            // B*NCH floats = 8 KB
    float* partial    = (float*)d_ws + 8192;     // [B*NCH, D] = 4.2 MB

    energy_exp_kernel<<<B * NCH / K1_CPB, 256, 0, stream>>>(q, k, mask, attn, chunk_sums);
    context_partial_kernel<<<B * NCH / K3_CPB, 256, 0, stream>>>(attn, v, chunk_sums, partial);
    context_reduce_kernel<<<B, 256, 0, stream>>>(partial, ctx);
}

// Round 12
// 109.993 us; speedup vs baseline: 1.0521x; 1.0351x over previous
//
#include <hip/hip_runtime.h>
#include <math.h>

#define B 64
#define T 4096
#define D 512
#define NCH 32            // 128-row chunks per batch row
#define CHT (T / NCH)     // 128 t per chunk
#define WSTRIP 32         // t-rows per wave in K1
#define KBATCH 4          // K rows per pipeline batch per wave in K1
#define VBATCH 8          // V rows per pipeline batch in K3

typedef __attribute__((address_space(1))) const void global_cv;
typedef __attribute__((address_space(3))) void lds_v;

__device__ __forceinline__ float wave_sum64(float v) {
#pragma unroll
    for (int off = 32; off; off >>= 1)
        v += __shfl_xor(v, off, 64);
    return v;
}

// Async-stage one 2KB row into LDS: 2 x (64 lanes x 16B) global_load_lds.
// LDS dest is the wave-uniform row base (HW adds lane*16); global src is
// per-lane. Increments vmcnt by 2 per call per wave.
__device__ __forceinline__ void stage_row(const float* __restrict__ gsrc_row,
                                          float* lds_row, int lane) {
    __builtin_amdgcn_global_load_lds((global_cv*)(gsrc_row + lane * 4),
                                     (lds_v*)(lds_row), 16, 0, 0);
    __builtin_amdgcn_global_load_lds((global_cv*)(gsrc_row + 256 + lane * 4),
                                     (lds_v*)(lds_row + 256), 16, 0, 0);
}

// K1 (R8 body + coalesced attn store): DMA-pipelined energy+exp. grid = B*32,
// block = 256 (4 waves x 32-row strip). Live rows compacted per wave; K rows
// stream through a per-wave 2x4-row LDS double buffer (global_load_lds,
// counted vmcnt(8), NO barriers -- waves fully independent). 4-row multiplexed
// butterfly from LDS; masked rows never read. g values staged in pre-zeroed
// per-wave sm_g; ONE coalesced 128B attn store per wave at strip end
// (replaces R8's scattered divergent 4B stores -- the only change vs R8).
__global__ __launch_bounds__(256) void energy_exp_kernel(const float* __restrict__ q,
                                                         const float* __restrict__ k,
                                                         const int* __restrict__ mask,
                                                         float* __restrict__ attn,
                                                         float* __restrict__ chunk_sums) {
    const float INV_SCALE = 0.04419417382415922f;  // 1/sqrt(512)

    __shared__ __align__(16) float kbuf[2][4][KBATCH][D];   // 64 KB
    __shared__ int sm_list[4][WSTRIP + KBATCH];
    __shared__ float sm_g[4][WSTRIP];
    __shared__ float sred[4];

    int blk = blockIdx.x;
    int b = blk >> 5;
    int ch = blk & 31;
    int wave = threadIdx.x >> 6;
    int lane = threadIdx.x & 63;

    const float* qb = q + b * D;
    float4 qa = *(const float4*)(qb + lane * 4);
    float4 qc = *(const float4*)(qb + 256 + lane * 4);

    int t0 = ch * CHT + wave * WSTRIP;
    const float* kbase = k + ((size_t)b * T + t0) * D;

    // 32-row mask bitmap + order-stable compaction (wave-local LDS list)
    int mv = (lane < WSTRIP) ? mask[b * T + t0 + lane] : 0;
    unsigned int mbits = (unsigned int)__ballot(mv != 0);
    int cnt = __popc(mbits);
    int row0 = (cnt > 0) ? (__ffs(mbits) - 1) : 0;   // uniform, no LDS read
    if (lane < WSTRIP) {
        sm_g[wave][lane] = 0.0f;            // masked rows stay exactly 0
        if (mv != 0) {
            int pre = __popc(mbits & ((1u << lane) - 1u));
            sm_list[wave][pre] = lane;
        }
    }
    if (lane < KBATCH) sm_list[wave][cnt + lane] = row0;  // pad slots

    int ngrp = (cnt + KBATCH - 1) >> 2;

    // prologue: stage batches 0 and 1 (4 rows = 8 vmcnt each, per wave)
    if (ngrp > 0) {
#pragma unroll
        for (int r = 0; r < KBATCH; ++r)
            stage_row(kbase + (size_t)sm_list[wave][r] * D, &kbuf[0][wave][r][0], lane);
    }
    if (ngrp > 1) {
#pragma unroll
        for (int r = 0; r < KBATCH; ++r)
            stage_row(kbase + (size_t)sm_list[wave][KBATCH + r] * D, &kbuf[1][wave][r][0], lane);
    }

    // slot owned by this lane after the 4-row butterfly: bits {5,4} -> {0,1}
    int r2 = ((lane >> 5) & 1) | (((lane >> 4) & 1) << 1);
    float gsum = 0.f;

#pragma unroll 1
    for (int i = 0; i < ngrp; ++i) {
        if (i + 1 < ngrp) asm volatile("s_waitcnt vmcnt(8)" ::: "memory");
        else              asm volatile("s_waitcnt vmcnt(0)" ::: "memory");

        const float (*buf)[D] = kbuf[i & 1][wave];
        float d4[KBATCH];
#pragma unroll
        for (int rr = 0; rr < KBATCH; ++rr) {
            float4 ka = *(const float4*)&buf[rr][lane * 4];
            float4 kc = *(const float4*)&buf[rr][256 + lane * 4];
            d4[rr] = ka.x * qa.x + ka.y * qa.y + ka.z * qa.z + ka.w * qa.w
                   + kc.x * qc.x + kc.y * qc.y + kc.z * qc.z + kc.w * qc.w;
        }
        // ds_reads of this buffer complete before re-staging over it
        asm volatile("s_waitcnt lgkmcnt(0)" ::: "memory");
        if (i + 2 < ngrp) {
            int s0 = (i + 2) * KBATCH;
#pragma unroll
            for (int r = 0; r < KBATCH; ++r)
                stage_row(kbase + (size_t)sm_list[wave][s0 + r] * D,
                          &kbuf[i & 1][wave][r][0], lane);
        }

        // multiplexed butterfly: 4 slots x 64 lanes -> full dots in 7 shuffles
        bool b5 = (lane & 32) != 0;
        float e[2];
#pragma unroll
        for (int j = 0; j < 2; ++j) {
            float u = b5 ? d4[2*j+1] : d4[2*j];
            float s = b5 ? d4[2*j]   : d4[2*j+1];
            e[j] = u + __shfl_xor(s, 32, 64);
        }
        bool b4 = (lane & 16) != 0;
        float u = b4 ? e[1] : e[0];
        float s = b4 ? e[0] : e[1];
        float h = u + __shfl_xor(s, 16, 64);
        h += __shfl_xor(h, 8, 64);
        h += __shfl_xor(h, 4, 64);
        h += __shfl_xor(h, 2, 64);
        h += __shfl_xor(h, 1, 64);
        // h = dot for slot (i*4 + r2), replicated on 16 lanes (bits 3..0 free)

        int slot = i * KBATCH + r2;
        float gval = 0.f;
        if (slot < cnt) {
            gval = __expf(h * INV_SCALE);
            if ((lane & 15) == 0)
                sm_g[wave][sm_list[wave][slot]] = gval;   // wave-local LDS
        }
        gsum += gval;
    }

    // ONE coalesced 128B attn store per wave (unnormalized; K3 rescales)
    if (lane < WSTRIP)
        attn[(size_t)b * T + t0 + lane] = sm_g[wave][lane];

    // wave chunk-sum (each live row's g replicated on 16 lanes -> /16)
    float ws = wave_sum64(gsum) * 0.0625f;
    if (lane == 0) sred[wave] = ws;
    __syncthreads();
    if (threadIdx.x == 0)
        chunk_sums[blk] = (sred[0] + sred[1]) + (sred[2] + sred[3]);
}

// K3 (unchanged from R8): DMA-pipelined V accumulation. grid = B*NCH.
__global__ __launch_bounds__(256) void context_partial_kernel(float* __restrict__ attn,
                                                              const float* __restrict__ v,
                                                              const float* __restrict__ chunk_sums,
                                                              float* __restrict__ partial) {
    __shared__ __align__(16) float vbuf[2][VBATCH][D];   // 32 KB
    __shared__ float sa_raw[CHT];
    __shared__ int   rows[CHT + VBATCH];
    __shared__ float avals[CHT + VBATCH];
    __shared__ int   scnt;

    int blk = blockIdx.x;
    int b = blk >> 5;
    int ch = blk & 31;
    int tid = threadIdx.x;
    int wave = tid >> 6;
    int lane = tid & 63;

    float cs = (lane < NCH) ? chunk_sums[b * NCH + lane] : 0.f;
    float denom = wave_sum64(cs);
    float inv = 1.0f / denom;

    if (tid < CHT) sa_raw[tid] = attn[(size_t)b * T + ch * CHT + tid];
    __syncthreads();

    if (wave == 0) {
        float a0 = sa_raw[lane];
        unsigned long long bl0 = __ballot(a0 != 0.0f);
        int c0 = __popcll(bl0);
        if (a0 != 0.0f) {
            int p = __popcll(bl0 & ((1ull << lane) - 1ull));
            rows[p] = lane; avals[p] = a0;
        }
        float a1 = sa_raw[64 + lane];
        unsigned long long bl1 = __ballot(a1 != 0.0f);
        int c1 = __popcll(bl1);
        if (a1 != 0.0f) {
            int p = c0 + __popcll(bl1 & ((1ull << lane) - 1ull));
            rows[p] = 64 + lane; avals[p] = a1;
        }
        int cnt = c0 + c1;
        if (lane < VBATCH) {
            int safe0 = (cnt > 0) ? rows[0] : 0;
            rows[cnt + lane] = safe0;
            avals[cnt + lane] = 0.0f;
        }
        if (lane == 0) scnt = cnt;
    }
    __syncthreads();

    int cnt = scnt;
    int nb = (cnt + VBATCH - 1) / VBATCH;
    const float* vchunk = v + ((size_t)b * T + ch * CHT) * D;

    if (nb > 0) {
        int s0 = wave * 2;
        stage_row(vchunk + (size_t)rows[s0] * D,     &vbuf[0][wave * 2][0],     lane);
        stage_row(vchunk + (size_t)rows[s0 + 1] * D, &vbuf[0][wave * 2 + 1][0], lane);
    }
    if (nb > 1) {
        int s0 = VBATCH + wave * 2;
        stage_row(vchunk + (size_t)rows[s0] * D,     &vbuf[1][wave * 2][0],     lane);
        stage_row(vchunk + (size_t)rows[s0 + 1] * D, &vbuf[1][wave * 2 + 1][0], lane);
    }

    float2 acc = {0.f, 0.f};
    int c0 = tid * 2;
#pragma unroll 1
    for (int i = 0; i < nb; ++i) {
        if (i + 1 < nb) asm volatile("s_waitcnt vmcnt(4)" ::: "memory");
        else            asm volatile("s_waitcnt vmcnt(0)" ::: "memory");
        __builtin_amdgcn_s_barrier();

        const float (*buf)[D] = vbuf[i & 1];
        int base = i * VBATCH;
#pragma unroll
        for (int r = 0; r < VBATCH; ++r) {
            float a = avals[base + r];
            float2 vv = *(const float2*)&buf[r][c0];
            acc.x += a * vv.x;
            acc.y += a * vv.y;
        }
        __builtin_amdgcn_s_barrier();

        if (i + 2 < nb) {
            int s0 = (i + 2) * VBATCH + wave * 2;
            stage_row(vchunk + (size_t)rows[s0] * D,     &vbuf[i & 1][wave * 2][0],     lane);
            stage_row(vchunk + (size_t)rows[s0 + 1] * D, &vbuf[i & 1][wave * 2 + 1][0], lane);
        }
    }

    acc.x *= inv; acc.y *= inv;
    *(float2*)(partial + (size_t)(b * NCH + ch) * D + c0) = acc;

    if (tid < CHT)
        attn[(size_t)b * T + ch * CHT + tid] = sa_raw[tid] * inv;
}

// K4: reduce 32 partial rows -> context. grid = B, block = 256.
__global__ __launch_bounds__(256) void context_reduce_kernel(const float* __restrict__ partial,
                                                             float* __restrict__ ctx) {
    int b = blockIdx.x;
    int tid = threadIdx.x;
    int d0 = tid * 2;
    float2 acc = {0.f, 0.f};
#pragma unroll 8
    for (int j = 0; j < NCH; ++j) {
        float2 p = *(const float2*)(partial + (size_t)(b * NCH + j) * D + d0);
        acc.x += p.x;
        acc.y += p.y;
    }
    *(float2*)(ctx + (size_t)b * D + d0) = acc;
}

extern "C" void kernel_launch(void* const* d_in, const int* in_sizes, int n_in,
                              void* d_out, int out_size, void* d_ws, size_t ws_size,
                              hipStream_t stream) {
    const float* q    = (const float*)d_in[0];
    const float* k    = (const float*)d_in[1];
    const float* v    = (const float*)d_in[2];
    const int*   mask = (const int*)d_in[3];

    float* ctx  = (float*)d_out;            // [B, D]
    float* attn = (float*)d_out + B * D;    // [B, T]

    float* chunk_sums = (float*)d_ws;            // B*NCH floats = 8 KB
    float* partial    = (float*)d_ws + 8192;     // [B*NCH, D] = 4.2 MB

    energy_exp_kernel<<<B * NCH, 256, 0, stream>>>(q, k, mask, attn, chunk_sums);
    context_partial_kernel<<<B * NCH, 256, 0, stream>>>(attn, v, chunk_sums, partial);
    context_reduce_kernel<<<B, 256, 0, stream>>>(partial, ctx);
}